// Round 5
// baseline (15.283 us; speedup 1.0000x reference)
//
#include <hip/hip_runtime.h>
#include <math.h>

#define WIRES 4
#define DIM 16
#define OUT_C 16
#define QDEPTH 2
#define H 128
#define W 128
#define B 16

typedef __attribute__((ext_vector_type(4))) float f32x4;
typedef __attribute__((ext_vector_type(2))) float f32x2;

// ---------------------------------------------------------------------------
// Single fused kernel, 512 blocks x 256 threads x 2 px/thread (2 blocks/CU,
// 2 waves/SIMD -> latency hiding that round 4's 1-wave/SIMD config lacked).
// Each block: wave 0 rebuilds the 16x16 circuit unitary (parallel trig,
// 16-lane column evolution — verified since round 2), records staged in LDS:
//   rec k (32 floats): [0..8]=Ur[k][0..8], [9]=dR[k]=0.01*sum_{j>=9}Ur[k][j]
//                      [16..24]=Ui[k][0..8], [25]=dI[k]=0.01*sum Ui
// out[b][k][y][x] = min(8*((Ur[k].p)^2+(Ui[k].p)^2)/||p||^2, 1)
// ---------------------------------------------------------------------------
__global__ __launch_bounds__(256) void qconv_fused(const float* __restrict__ x,
                                                   const float* __restrict__ w,
                                                   float* __restrict__ out) {
    __shared__ float Utr[DIM][DIM];
    __shared__ float Uti[DIM][DIM];
    __shared__ float recs[512];

    const int tid = threadIdx.x;
    const int gid = blockIdx.x * 256 + tid;     // 131072 threads, 2 px each
    const int xg = (gid & 63) << 1;             // x0 in {0,2,...,126}
    const int yc = (gid >> 6) & (H - 1);
    const int b  = gid >> 13;

    const float* img = x + b * (H * W);

    // ---- 1) patch row window x0-1..x0+2 for 3 rows, +0.01, OOB -> 0.01 ----
    float r[3][4];
#pragma unroll
    for (int dy = 0; dy < 3; ++dy) {
        int yy = yc + dy - 1;
        int yyc = min(max(yy, 0), H - 1);
        bool rowok = (yy == yyc);
#pragma unroll
        for (int m = 0; m < 4; ++m) {
            int xx = xg + m - 1;
            int xxc = min(max(xx, 0), W - 1);
            float v = img[yyc * W + xxc];
            bool ok = rowok & (xx == xxc);
            r[dy][m] = (ok ? v : 0.f) + 0.01f;
        }
    }

    // ---- 2) wave 0: build U ----
    if (tid < 64) {
        // parallel trig: lane L -> gate g=L/6, element e=L%6
        // e: 0=cos(th/2) 1=sin(th/2) 2=cos(ap) 3=sin(ap) 4=cos(am) 5=sin(am)
        int g = tid / 6;
        int e = tid - 6 * g;
        int gg = g < 8 ? g : 7;
        float phi   = w[gg * 3 + 0];
        float theta = w[gg * 3 + 1];
        float omega = w[gg * 3 + 2];
        float ang = (e < 2) ? 0.5f * theta
                  : ((e < 4) ? 0.5f * (phi + omega) : 0.5f * (phi - omega));
        float sn = __sinf(ang);
        float cs = __cosf(ang);
        float trig = (e & 1) ? sn : cs;

        int col = tid & (DIM - 1);
        float sr[DIM], si[DIM];
#pragma unroll
        for (int i = 0; i < DIM; ++i) { sr[i] = 0.f; si[i] = 0.f; }
        sr[col] = 1.f;

#pragma unroll
        for (int l = 0; l < QDEPTH; ++l) {
#pragma unroll
            for (int q = 0; q < WIRES; ++q) {
                int gb = (l * WIRES + q) * 6;
                float c  = __shfl(trig, gb + 0);
                float s  = __shfl(trig, gb + 1);
                float cp = __shfl(trig, gb + 2);
                float sp = __shfl(trig, gb + 3);
                float cm = __shfl(trig, gb + 4);
                float sm = __shfl(trig, gb + 5);
                // ep = cp - i*sp ; em = cm - i*sm
                float u00r = cp * c,  u00i = -sp * c;
                float u01r = -cm * s, u01i = -sm * s;
                float u10r = cm * s,  u10i = -sm * s;
                float u11r = cp * c,  u11i = sp * c;

                const int m = 8 >> q;
#pragma unroll
                for (int i0 = 0; i0 < DIM; ++i0) {
                    if (i0 & m) continue;
                    int i1 = i0 | m;
                    float ar = sr[i0], ai = si[i0];
                    float br = sr[i1], bi = si[i1];
                    sr[i0] = u00r * ar - u00i * ai + u01r * br - u01i * bi;
                    si[i0] = u00r * ai + u00i * ar + u01r * bi + u01i * br;
                    sr[i1] = u10r * ar - u10i * ai + u11r * br - u11i * bi;
                    si[i1] = u10r * ai + u10i * ar + u11r * bi + u11i * br;
                }
            }
            const int rr = (l % (WIRES - 1)) + 1;
#pragma unroll
            for (int i = 0; i < WIRES; ++i) {
                const int mc = 8 >> i;
                const int mt = 8 >> ((i + rr) & (WIRES - 1));
#pragma unroll
                for (int i0 = 0; i0 < DIM; ++i0) {
                    if (!(i0 & mc)) continue;
                    if (i0 & mt) continue;
                    int i1 = i0 | mt;
                    float tr = sr[i0], ti = si[i0];
                    sr[i0] = sr[i1]; si[i0] = si[i1];
                    sr[i1] = tr;     si[i1] = ti;
                }
            }
        }

        if (tid < DIM) {
#pragma unroll
            for (int row = 0; row < DIM; ++row) {
                Utr[row][tid] = sr[row];
                Uti[row][tid] = si[row];
            }
        }
    }
    __syncthreads();

    if (tid < DIM) {
        int k = tid;
        float accR = 0.f, accI = 0.f;
#pragma unroll
        for (int j = 0; j < 9; ++j) {
            recs[k * 32 + j]      = Utr[k][j];
            recs[k * 32 + 16 + j] = Uti[k][j];
        }
#pragma unroll
        for (int j = 9; j < DIM; ++j) {
            accR += Utr[k][j];
            accI += Uti[k][j];
        }
        recs[k * 32 + 9]  = 0.01f * accR;
        recs[k * 32 + 25] = 0.01f * accI;
    }
    __syncthreads();

    // ---- 3) evaluate 2 pixels x 16 channels ----
    float scale[2];
#pragma unroll
    for (int i = 0; i < 2; ++i) {
        float n2 = 7.0f * 1e-4f;    // 7 tail entries of 0.01^2
#pragma unroll
        for (int dy = 0; dy < 3; ++dy)
#pragma unroll
            for (int dj = 0; dj < 3; ++dj) {
                float pv = r[dy][i + dj];
                n2 = fmaf(pv, pv, n2);
            }
        scale[i] = 8.0f / n2;       // (DIM*0.5)/||p||^2
    }

    float* o = out + ((size_t)b * OUT_C) * (H * W) + yc * W + xg;

#pragma unroll
    for (int k = 0; k < OUT_C; ++k) {
        const float* rec = &recs[k * 32];           // 128B-aligned
        f32x4 ra0 = *(const f32x4*)(rec);           // Ur[0..3]
        f32x4 ra1 = *(const f32x4*)(rec + 4);       // Ur[4..7]
        float r8  = rec[8];
        float dR  = rec[9];
        f32x4 ia0 = *(const f32x4*)(rec + 16);      // Ui[0..3]
        f32x4 ia1 = *(const f32x4*)(rec + 20);      // Ui[4..7]
        float i8  = rec[24];
        float dI  = rec[25];

        f32x2 res;
#pragma unroll
        for (int i = 0; i < 2; ++i) {
            float u = dR;
            float v = dI;
#pragma unroll
            for (int j = 0; j < 9; ++j) {
                float cR = (j < 4) ? ra0[j & 3] : ((j < 8) ? ra1[j & 3] : r8);
                float cI = (j < 4) ? ia0[j & 3] : ((j < 8) ? ia1[j & 3] : i8);
                float pv = r[j / 3][i + (j % 3)];
                u = fmaf(cR, pv, u);
                v = fmaf(cI, pv, v);
            }
            float val = fmaf(u, u, v * v) * scale[i];
            res[i] = fminf(val, 1.0f);
        }
        *(f32x2*)(o + (size_t)k * (H * W)) = res;   // 8B-aligned (xg%2==0)
    }
}

extern "C" void kernel_launch(void* const* d_in, const int* in_sizes, int n_in,
                              void* d_out, int out_size, void* d_ws, size_t ws_size,
                              hipStream_t stream) {
    const float* x = (const float*)d_in[0];        // [16,1,128,128] f32
    const float* w = (const float*)d_in[1];        // [2,4,3] f32
    float* out = (float*)d_out;                    // [16,16,128,128] f32

    // 512 blocks x 256 threads x 2 px = 262144 pixels, single dispatch
    qconv_fused<<<512, 256, 0, stream>>>(x, w, out);
}

// Round 6
// 14.991 us; speedup vs baseline: 1.0195x; 1.0195x over previous
//
#include <hip/hip_runtime.h>
#include <math.h>

#define WIRES 4
#define DIM 16
#define OUT_C 16
#define QDEPTH 2
#define H 128
#define W 128
#define B 16

typedef __attribute__((ext_vector_type(4))) float f32x4;

// ---------------------------------------------------------------------------
// Single fused kernel (best-measured config: 256 blocks x 256 threads x 4 px).
// Each block: wave 0 rebuilds the 16x16 circuit unitary (parallel trig across
// lanes, 16-lane column evolution — verified since round 2), records staged
// in LDS:
//   rec k (32 floats): [0..8]=Ur[k][0..8], [9]=dR[k]=0.01*sum_{j>=9}Ur[k][j]
//                      [16..24]=Ui[k][0..8], [25]=dI[k]=0.01*sum Ui
// out[b][k][y][x] = min(8*((Ur[k].p)^2+(Ui[k].p)^2)/||p||^2, 1)
//
// Perf ledger (MI355X, harness-timed):
//   2 dispatches, any kernel internals:    ~20.9-21.7 us
//   1 fused dispatch, 4 px/thread:          14.99 us   <- this config
//   1 fused dispatch, 2 px/thread, 2x occ:  15.28 us   (null -> not latency-bound)
// Kernel GPU work ~3 us (2.7 us write roofline + ~1.2 us VALU); remainder is
// fixed per-replay launch/graph overhead -> single-dispatch floor.
// ---------------------------------------------------------------------------
__global__ __launch_bounds__(256) void qconv_fused(const float* __restrict__ x,
                                                   const float* __restrict__ w,
                                                   float* __restrict__ out) {
    __shared__ float Utr[DIM][DIM];
    __shared__ float Uti[DIM][DIM];
    __shared__ float recs[512];

    const int tid = threadIdx.x;
    const int gid = blockIdx.x * 256 + tid;     // 65536 threads, 4 px each
    const int xg = (gid & 31) << 2;             // x0 in {0,4,...,124}
    const int yc = (gid >> 5) & (H - 1);
    const int b  = gid >> 12;

    const float* img = x + b * (H * W);

    // ---- 1) patch row window x0-1..x0+4 for 3 rows, +0.01, OOB -> 0.01 ----
    float r[3][6];
#pragma unroll
    for (int dy = 0; dy < 3; ++dy) {
        int yy = yc + dy - 1;
        int yyc = min(max(yy, 0), H - 1);
        bool rowok = (yy == yyc);
#pragma unroll
        for (int m = 0; m < 6; ++m) {
            int xx = xg + m - 1;
            int xxc = min(max(xx, 0), W - 1);
            float v = img[yyc * W + xxc];
            bool ok = rowok & (xx == xxc);
            r[dy][m] = (ok ? v : 0.f) + 0.01f;
        }
    }

    // ---- 2) wave 0: build U ----
    if (tid < 64) {
        // parallel trig: lane L -> gate g=L/6, element e=L%6
        // e: 0=cos(th/2) 1=sin(th/2) 2=cos(ap) 3=sin(ap) 4=cos(am) 5=sin(am)
        int g = tid / 6;
        int e = tid - 6 * g;
        int gg = g < 8 ? g : 7;
        float phi   = w[gg * 3 + 0];
        float theta = w[gg * 3 + 1];
        float omega = w[gg * 3 + 2];
        float ang = (e < 2) ? 0.5f * theta
                  : ((e < 4) ? 0.5f * (phi + omega) : 0.5f * (phi - omega));
        float sn = __sinf(ang);
        float cs = __cosf(ang);
        float trig = (e & 1) ? sn : cs;

        int col = tid & (DIM - 1);
        float sr[DIM], si[DIM];
#pragma unroll
        for (int i = 0; i < DIM; ++i) { sr[i] = 0.f; si[i] = 0.f; }
        sr[col] = 1.f;

#pragma unroll
        for (int l = 0; l < QDEPTH; ++l) {
#pragma unroll
            for (int q = 0; q < WIRES; ++q) {
                int gb = (l * WIRES + q) * 6;
                float c  = __shfl(trig, gb + 0);
                float s  = __shfl(trig, gb + 1);
                float cp = __shfl(trig, gb + 2);
                float sp = __shfl(trig, gb + 3);
                float cm = __shfl(trig, gb + 4);
                float sm = __shfl(trig, gb + 5);
                // ep = cp - i*sp ; em = cm - i*sm
                float u00r = cp * c,  u00i = -sp * c;
                float u01r = -cm * s, u01i = -sm * s;
                float u10r = cm * s,  u10i = -sm * s;
                float u11r = cp * c,  u11i = sp * c;

                const int m = 8 >> q;
#pragma unroll
                for (int i0 = 0; i0 < DIM; ++i0) {
                    if (i0 & m) continue;
                    int i1 = i0 | m;
                    float ar = sr[i0], ai = si[i0];
                    float br = sr[i1], bi = si[i1];
                    sr[i0] = u00r * ar - u00i * ai + u01r * br - u01i * bi;
                    si[i0] = u00r * ai + u00i * ar + u01r * bi + u01i * br;
                    sr[i1] = u10r * ar - u10i * ai + u11r * br - u11i * bi;
                    si[i1] = u10r * ai + u10i * ar + u11r * bi + u11i * br;
                }
            }
            const int rr = (l % (WIRES - 1)) + 1;
#pragma unroll
            for (int i = 0; i < WIRES; ++i) {
                const int mc = 8 >> i;
                const int mt = 8 >> ((i + rr) & (WIRES - 1));
#pragma unroll
                for (int i0 = 0; i0 < DIM; ++i0) {
                    if (!(i0 & mc)) continue;
                    if (i0 & mt) continue;
                    int i1 = i0 | mt;
                    float tr = sr[i0], ti = si[i0];
                    sr[i0] = sr[i1]; si[i0] = si[i1];
                    sr[i1] = tr;     si[i1] = ti;
                }
            }
        }

        if (tid < DIM) {
#pragma unroll
            for (int row = 0; row < DIM; ++row) {
                Utr[row][tid] = sr[row];
                Uti[row][tid] = si[row];
            }
        }
    }
    __syncthreads();

    if (tid < DIM) {
        int k = tid;
        float accR = 0.f, accI = 0.f;
#pragma unroll
        for (int j = 0; j < 9; ++j) {
            recs[k * 32 + j]      = Utr[k][j];
            recs[k * 32 + 16 + j] = Uti[k][j];
        }
#pragma unroll
        for (int j = 9; j < DIM; ++j) {
            accR += Utr[k][j];
            accI += Uti[k][j];
        }
        recs[k * 32 + 9]  = 0.01f * accR;
        recs[k * 32 + 25] = 0.01f * accI;
    }
    __syncthreads();

    // ---- 3) evaluate 4 pixels x 16 channels ----
    float scale[4];
#pragma unroll
    for (int i = 0; i < 4; ++i) {
        float n2 = 7.0f * 1e-4f;    // 7 tail entries of 0.01^2
#pragma unroll
        for (int dy = 0; dy < 3; ++dy)
#pragma unroll
            for (int dj = 0; dj < 3; ++dj) {
                float pv = r[dy][i + dj];
                n2 = fmaf(pv, pv, n2);
            }
        scale[i] = 8.0f / n2;       // (DIM*0.5)/||p||^2
    }

    float* o = out + ((size_t)b * OUT_C) * (H * W) + yc * W + xg;

#pragma unroll
    for (int k = 0; k < OUT_C; ++k) {
        const float* rec = &recs[k * 32];           // 128B-aligned
        f32x4 ra0 = *(const f32x4*)(rec);           // Ur[0..3]
        f32x4 ra1 = *(const f32x4*)(rec + 4);       // Ur[4..7]
        float r8  = rec[8];
        float dR  = rec[9];
        f32x4 ia0 = *(const f32x4*)(rec + 16);      // Ui[0..3]
        f32x4 ia1 = *(const f32x4*)(rec + 20);      // Ui[4..7]
        float i8  = rec[24];
        float dI  = rec[25];

        f32x4 res;
#pragma unroll
        for (int i = 0; i < 4; ++i) {
            float u = dR;
            float v = dI;
#pragma unroll
            for (int j = 0; j < 9; ++j) {
                float cR = (j < 4) ? ra0[j & 3] : ((j < 8) ? ra1[j & 3] : r8);
                float cI = (j < 4) ? ia0[j & 3] : ((j < 8) ? ia1[j & 3] : i8);
                float pv = r[j / 3][i + (j % 3)];
                u = fmaf(cR, pv, u);
                v = fmaf(cI, pv, v);
            }
            float val = fmaf(u, u, v * v) * scale[i];
            res[i] = fminf(val, 1.0f);
        }
        *(f32x4*)(o + (size_t)k * (H * W)) = res;   // 16B-aligned (xg%4==0)
    }
}

extern "C" void kernel_launch(void* const* d_in, const int* in_sizes, int n_in,
                              void* d_out, int out_size, void* d_ws, size_t ws_size,
                              hipStream_t stream) {
    const float* x = (const float*)d_in[0];        // [16,1,128,128] f32
    const float* w = (const float*)d_in[1];        // [2,4,3] f32
    float* out = (float*)d_out;                    // [16,16,128,128] f32

    // 256 blocks x 256 threads x 4 px = 262144 pixels, single dispatch
    qconv_fused<<<256, 256, 0, stream>>>(x, w, out);
}